// Round 2
// baseline (5688.243 us; speedup 1.0000x reference)
//
#include <hip/hip_runtime.h>

#define NN 20000
#define NE 320000
#define CDIM 16
#define MID 32
#define EPSF 1e-8f

// ---- workspace float offsets ----
#define OFF_STATS1 0           //   8
#define OFF_STATS2 8           // 384  ([k][{sum,sq}][j])
#define OFF_DEG    392         // 20000
#define OFF_AGG0   20392       // 320000
#define OFF_AGG1   340392      // 960000
#define OFF_OUTACC 1300392     // 120000
#define ZERO_FLOATS 1420392
#define OFF_FW1A   1420392     // 192  (6*32)  W1[0]*a1
#define OFF_FW1B   1420584     // 192  W1[1]*a1
#define OFF_FC1    1420776     // 192  folded layer1 const
#define OFF_BN2A   1420968     // 192  a2
#define OFF_FC2    1421160     // 192  folded layer2 const
#define OFF_FW2T   1421352     // 6144 ([k][j][i] = W2[k][i][j]*a2[k][j])
#define OFF_ECACHE 1427496     // E*4 (float4: r,ux,uy,uz)
#define OFF_H0N    2707496     // 320000
#define OFF_H1N    3027496     // 960000
// total = 3987496 floats ~ 16.0 MB

// spherical-harmonic constants
#define Y0C   0.28209479177387814f
#define Y1C   0.4886025119029199f
#define Y2C1  1.0925484305920792f
#define Y2C2  0.31539156525252005f
#define Y2C3  0.5462742152960396f
#define S2C   0.7071067811865476f
#define S6C   0.4082482904638631f
#define K0C   0.16286750396763996f   // Y0/sqrt(3)

__device__ __forceinline__ void atomAddF(float* p, float v) {
  unsafeAtomicAdd(p, v);   // HW global_atomic_add_f32 on gfx950
}

// Folded 2-layer MLP, all weights in LDS (broadcast reads, b128-vectorized).
__device__ __forceinline__ void mlpH_lds(
    const float* __restrict__ a1, const float* __restrict__ b1v,
    const float* __restrict__ c1, const float* __restrict__ c2,
    const float* __restrict__ W2T, float we, float r, float* H) {
  float h[MID];
#pragma unroll
  for (int j = 0; j < MID; ++j)
    h[j] = fmaxf(fmaf(we, a1[j], fmaf(r, b1v[j], c1[j])), 0.0f);
#pragma unroll
  for (int j = 0; j < MID; ++j) {
    float acc = c2[j];
#pragma unroll
    for (int i = 0; i < MID; ++i) acc = fmaf(h[i], W2T[j * MID + i], acc);
    H[j] = fmaxf(acc, 0.0f);
  }
}

// ---- pass 1: edge geometry cache, degree, layer-1 stat scalars ----
__global__ __launch_bounds__(256) void k_pass1(
    const int* __restrict__ src, const int* __restrict__ dst,
    const float* __restrict__ pos, const float* __restrict__ w,
    float* __restrict__ ws) {
  float lw = 0, lr = 0, lww = 0, lrr = 0, lwr = 0;
  float* deg = ws + OFF_DEG;
  float4* ec = (float4*)(ws + OFF_ECACHE);
  for (int e = blockIdx.x * blockDim.x + threadIdx.x; e < NE;
       e += gridDim.x * blockDim.x) {
    int s = src[e], d = dst[e];
    float dx = pos[3 * d + 0] - pos[3 * s + 0];
    float dy = pos[3 * d + 1] - pos[3 * s + 1];
    float dz = pos[3 * d + 2] - pos[3 * s + 2];
    float r = sqrtf(dx * dx + dy * dy + dz * dz);
    float ri = 1.0f / fmaxf(r, EPSF);
    ec[e] = make_float4(r, dx * ri, dy * ri, dz * ri);
    float we = w[e];
    lw += we; lr += r; lww += we * we; lrr += r * r; lwr += we * r;
    atomAddF(deg + d, 1.0f);
  }
#pragma unroll
  for (int d = 32; d >= 1; d >>= 1) {
    lw += __shfl_xor(lw, d);
    lr += __shfl_xor(lr, d);
    lww += __shfl_xor(lww, d);
    lrr += __shfl_xor(lrr, d);
    lwr += __shfl_xor(lwr, d);
  }
  if ((threadIdx.x & 63) == 0) {
    atomAddF(ws + OFF_STATS1 + 0, lw);
    atomAddF(ws + OFF_STATS1 + 1, lr);
    atomAddF(ws + OFF_STATS1 + 2, lww);
    atomAddF(ws + OFF_STATS1 + 3, lrr);
    atomAddF(ws + OFF_STATS1 + 4, lwr);
  }
}

// ---- finalize BN layer 1 (analytic) -> folded layer1 weights ----
__global__ void k_fin1(const float* __restrict__ rW1, const float* __restrict__ rb1,
                       const float* __restrict__ rg1, const float* __restrict__ rbe1,
                       float* __restrict__ ws) {
  int t = threadIdx.x;  // 0..191
  int k = t >> 5, j = t & 31;
  float Sw = ws[OFF_STATS1 + 0], Sr = ws[OFF_STATS1 + 1];
  float Sww = ws[OFF_STATS1 + 2], Srr = ws[OFF_STATS1 + 3], Swr = ws[OFF_STATS1 + 4];
  const float inv = 1.0f / (float)NE;
  float W0 = rW1[k * 64 + j], W1 = rW1[k * 64 + 32 + j], b = rb1[k * 32 + j];
  float mlin = (Sw * W0 + Sr * W1) * inv;
  float mu = mlin + b;
  float ex2 = (Sww * W0 * W0 + Srr * W1 * W1 + 2.0f * Swr * W0 * W1) * inv
            + 2.0f * b * mlin + b * b;
  float var = ex2 - mu * mu;
  float a = rg1[k * 32 + j] * rsqrtf(var + 1e-5f);
  ws[OFF_FW1A + t] = W0 * a;
  ws[OFF_FW1B + t] = W1 * a;
  ws[OFF_FC1 + t] = rbe1[k * 32 + j] - mlin * a;   // = be + (b-mu)*a
}

// ---- pass 2: layer-2 pre-activation stats (per network via blockIdx.y) ----
__global__ __launch_bounds__(256) void k_stats2(
    const float* __restrict__ w,
    const float* __restrict__ rW2, const float* __restrict__ rb2,
    float* __restrict__ ws) {
  const int k = blockIdx.y;
  __shared__ __align__(16) float sW1a[32], sW1b[32], sc1[32], sb2[32];
  __shared__ __align__(16) float sW2T[1024];
  int tid = threadIdx.x;
  if (tid < 32) {
    sW1a[tid] = ws[OFF_FW1A + k * 32 + tid];
    sW1b[tid] = ws[OFF_FW1B + k * 32 + tid];
    sc1[tid] = ws[OFF_FC1 + k * 32 + tid];
    sb2[tid] = rb2[k * 32 + tid];
  }
  for (int t = tid; t < 1024; t += 256) {
    int i = t >> 5, j = t & 31;
    sW2T[j * 32 + i] = rW2[k * 1024 + i * 32 + j];
  }
  __syncthreads();
  const float4* ec = (const float4*)(ws + OFF_ECACHE);
  float lsum[MID], lsq[MID];
#pragma unroll
  for (int j = 0; j < MID; ++j) { lsum[j] = 0.0f; lsq[j] = 0.0f; }
  for (int e = blockIdx.x * blockDim.x + tid; e < NE;
       e += gridDim.x * blockDim.x) {
    float r = ec[e].x;
    float we = w[e];
    float h[MID];
#pragma unroll
    for (int j = 0; j < MID; ++j)
      h[j] = fmaxf(fmaf(we, sW1a[j], fmaf(r, sW1b[j], sc1[j])), 0.0f);
#pragma unroll
    for (int j = 0; j < MID; ++j) {
      float acc = sb2[j];
#pragma unroll
      for (int i = 0; i < MID; ++i) acc = fmaf(h[i], sW2T[j * 32 + i], acc);
      lsum[j] += acc;
      lsq[j] = fmaf(acc, acc, lsq[j]);
    }
  }
#pragma unroll
  for (int j = 0; j < MID; ++j) {
    float v1 = lsum[j], v2 = lsq[j];
#pragma unroll
    for (int d = 32; d >= 1; d >>= 1) {
      v1 += __shfl_xor(v1, d);
      v2 += __shfl_xor(v2, d);
    }
    if ((tid & 63) == 0) {
      atomAddF(ws + OFF_STATS2 + k * 64 + j, v1);
      atomAddF(ws + OFF_STATS2 + k * 64 + 32 + j, v2);
    }
  }
}

// ---- finalize BN layer 2 ----
__global__ void k_fin2(const float* __restrict__ rb2,
                       const float* __restrict__ rg2, const float* __restrict__ rbe2,
                       float* __restrict__ ws) {
  int t = threadIdx.x;  // 0..191
  int k = t >> 5, j = t & 31;
  const float inv = 1.0f / (float)NE;
  float mu = ws[OFF_STATS2 + k * 64 + j] * inv;
  float ex2 = ws[OFF_STATS2 + k * 64 + 32 + j] * inv;
  float var = ex2 - mu * mu;
  float a = rg2[t] * rsqrtf(var + 1e-5f);
  ws[OFF_BN2A + t] = a;
  ws[OFF_FC2 + t] = rbe2[t] + (rb2[t] - mu) * a;
}

// ---- fold a2 into W2, transposed: fW2T[k][j][i] = W2[k][i][j]*a2[k][j] ----
__global__ __launch_bounds__(256) void k_fold2(const float* __restrict__ rW2,
                                               float* __restrict__ ws) {
  int idx = blockIdx.x * blockDim.x + threadIdx.x;  // 0..6143
  if (idx >= 6144) return;
  int k = idx >> 10, rem = idx & 1023;
  int j = rem >> 5, i = rem & 31;
  ws[OFF_FW2T + idx] = rW2[k * 1024 + i * 32 + j] * ws[OFF_BN2A + k * 32 + j];
}

// ---- stage A: per-edge messages m0 (C), m1 (C,3) -> atomic scatter ----
__global__ __launch_bounds__(256) void k_passA(
    const int* __restrict__ src, const int* __restrict__ dst,
    const float* __restrict__ cI, const float* __restrict__ vI,
    const float* __restrict__ w,
    const float* __restrict__ w00, const float* __restrict__ b00,
    const float* __restrict__ w01, const float* __restrict__ b01,
    const float* __restrict__ w10, const float* __restrict__ b10,
    const float* __restrict__ w11, const float* __restrict__ b11,
    float* __restrict__ ws) {
  __shared__ __align__(16) float sW1a[128], sW1b[128], sc1[128], sc2[128];
  __shared__ __align__(16) float sW2T[4096];
  __shared__ __align__(16) float sP00[512], sP01[512], sP10[512], sP11[1536];
  __shared__ __align__(16) float sB00[16], sB01[16], sB10[16], sB11[48];
  int tid = threadIdx.x;
  if (tid < 128) {
    sW1a[tid] = ws[OFF_FW1A + tid];
    sW1b[tid] = ws[OFF_FW1B + tid];
    sc1[tid] = ws[OFF_FC1 + tid];
    sc2[tid] = ws[OFF_FC2 + tid];
  }
  for (int t = tid; t < 4096; t += 256) sW2T[t] = ws[OFF_FW2T + t];
  for (int t = tid; t < 512; t += 256) {
    int i = t >> 4, co = t & 15;
    sP00[co * 32 + i] = w00[t];
    sP01[co * 32 + i] = w01[t];
    sP10[co * 32 + i] = w10[t];
  }
  for (int t = tid; t < 1536; t += 256) {
    int i = t / 48, c = t - i * 48;
    sP11[c * 32 + i] = w11[t];
  }
  if (tid < 16) { sB00[tid] = b00[tid]; sB01[tid] = b01[tid]; sB10[tid] = b10[tid]; }
  if (tid < 48) sB11[tid] = b11[tid];
  __syncthreads();

  const float4* ec = (const float4*)(ws + OFF_ECACHE);
  float* agg0 = ws + OFF_AGG0;
  float* agg1 = ws + OFF_AGG1;
  for (int e = blockIdx.x * blockDim.x + tid; e < NE;
       e += gridDim.x * blockDim.x) {
    int s = src[e], d = dst[e];
    float4 E4 = ec[e];
    float r = E4.x, ux = E4.y, uy = E4.z, uz = E4.w;
    float we = w[e];
    float cs = cI[s];
    float v0 = vI[3 * s + 0], v1 = vI[3 * s + 1], v2 = vI[3 * s + 2];
    float y10 = Y1C * uy, y11 = Y1C * uz, y12 = Y1C * ux;
    float y20 = Y2C1 * ux * uy, y21 = Y2C1 * uy * uz;
    float y22 = Y2C2 * (3.0f * uz * uz - 1.0f);
    float y23 = Y2C1 * ux * uz, y24 = Y2C3 * (ux * ux - uy * uy);
    float S00 = -S6C * y22 - S2C * y24;
    float S11 = 2.0f * S6C * y22;
    float S22 = -S6C * y22 + S2C * y24;
    float S01 = S2C * y21, S02 = S2C * y20, S12 = S2C * y23;
    float KV[3][3];
    KV[0][0] = K0C * v0; KV[0][1] = K0C * v1; KV[0][2] = K0C * v2;
    KV[1][0] = S2C * (y12 * v1 - y11 * v2);
    KV[1][1] = S2C * (y10 * v2 - y12 * v0);
    KV[1][2] = S2C * (y11 * v0 - y10 * v1);
    KV[2][0] = S00 * v0 + S01 * v1 + S02 * v2;
    KV[2][1] = S01 * v0 + S11 * v1 + S12 * v2;
    KV[2][2] = S02 * v0 + S12 * v1 + S22 * v2;
    float dY1v = y10 * v0 + y11 * v1 + y12 * v2;

    float H[MID];
    float m0[CDIM], m1[CDIM * 3];

    // net 0: m0 = R00 * Y0 * c_src
    mlpH_lds(sW1a, sW1b, sc1, sc2, sW2T, we, r, H);
    float f0 = Y0C * cs;
#pragma unroll
    for (int co = 0; co < CDIM; ++co) {
      float acc = sB00[co];
#pragma unroll
      for (int i = 0; i < MID; ++i) acc = fmaf(H[i], sP00[co * 32 + i], acc);
      m0[co] = acc * f0;
    }
    // net 2: m0 += R10 * (Y1 . v_src)
    mlpH_lds(sW1a + 64, sW1b + 64, sc1 + 64, sc2 + 64, sW2T + 2048, we, r, H);
#pragma unroll
    for (int co = 0; co < CDIM; ++co) {
      float acc = sB10[co];
#pragma unroll
      for (int i = 0; i < MID; ++i) acc = fmaf(H[i], sP10[co * 32 + i], acc);
      m0[co] = fmaf(acc, dY1v, m0[co]);
    }
    // net 1: m1 = R01 * c_src * Y1[a]
    mlpH_lds(sW1a + 32, sW1b + 32, sc1 + 32, sc2 + 32, sW2T + 1024, we, r, H);
    float cy0 = cs * y10, cy1 = cs * y11, cy2 = cs * y12;
#pragma unroll
    for (int co = 0; co < CDIM; ++co) {
      float acc = sB01[co];
#pragma unroll
      for (int i = 0; i < MID; ++i) acc = fmaf(H[i], sP01[co * 32 + i], acc);
      m1[co * 3 + 0] = acc * cy0;
      m1[co * 3 + 1] = acc * cy1;
      m1[co * 3 + 2] = acc * cy2;
    }
    // net 3: m1[co][a] += sum_f R11[co,f] * KV[f][a]
    mlpH_lds(sW1a + 96, sW1b + 96, sc1 + 96, sc2 + 96, sW2T + 3072, we, r, H);
#pragma unroll
    for (int co = 0; co < CDIM; ++co) {
#pragma unroll
      for (int f = 0; f < 3; ++f) {
        float acc = sB11[co * 3 + f];
#pragma unroll
        for (int i = 0; i < MID; ++i)
          acc = fmaf(H[i], sP11[(co * 3 + f) * 32 + i], acc);
        m1[co * 3 + 0] = fmaf(acc, KV[f][0], m1[co * 3 + 0]);
        m1[co * 3 + 1] = fmaf(acc, KV[f][1], m1[co * 3 + 1]);
        m1[co * 3 + 2] = fmaf(acc, KV[f][2], m1[co * 3 + 2]);
      }
    }
    float* p0 = agg0 + d * CDIM;
    float* p1 = agg1 + d * CDIM * 3;
#pragma unroll
    for (int co = 0; co < CDIM; ++co) atomAddF(p0 + co, m0[co]);
#pragma unroll
    for (int q = 0; q < CDIM * 3; ++q) atomAddF(p1 + q, m1[q]);
  }
}

// ---- node update A: normalize aggregates, norm_bias -> h0n, h1n ----
__global__ __launch_bounds__(256) void k_nodeA(
    const float* __restrict__ cI, const float* __restrict__ vI,
    const float* __restrict__ selfA0, const float* __restrict__ selfA1,
    const float* __restrict__ nbias0, const float* __restrict__ nbias1,
    float* __restrict__ ws) {
  int idx = blockIdx.x * blockDim.x + threadIdx.x;
  if (idx >= NN * CDIM) return;
  int n = idx >> 4, co = idx & 15;
  float dg = ws[OFF_DEG + n];
  float iv = 1.0f / fmaxf(dg, 1.0f);
  float mk = dg > 0.0f ? 1.0f : 0.0f;
  float x0 = ws[OFF_AGG0 + idx] * iv + selfA0[co] * cI[n] * mk;
  float n0 = sqrtf(x0 * x0 + 1e-12f);
  ws[OFF_H0N + idx] = fmaxf(n0 + nbias0[co], 0.0f) * (x0 / fmaxf(n0, EPSF));
  float xa = ws[OFF_AGG1 + idx * 3 + 0] * iv + selfA1[co] * vI[3 * n + 0] * mk;
  float xb = ws[OFF_AGG1 + idx * 3 + 1] * iv + selfA1[co] * vI[3 * n + 1] * mk;
  float xc = ws[OFF_AGG1 + idx * 3 + 2] * iv + selfA1[co] * vI[3 * n + 2] * mk;
  float nv = sqrtf(xa * xa + xb * xb + xc * xc + 1e-12f);
  float sc = fmaxf(nv + nbias1[co], 0.0f) / fmaxf(nv, EPSF);
  ws[OFF_H1N + idx * 3 + 0] = xa * sc;
  ws[OFF_H1N + idx * 3 + 1] = xb * sc;
  ws[OFF_H1N + idx * 3 + 2] = xc * sc;
}

// ---- stage B: per-edge output messages -> atomic scatter ----
__global__ __launch_bounds__(256) void k_passB(
    const int* __restrict__ src, const int* __restrict__ dst,
    const float* __restrict__ w,
    const float* __restrict__ wb01, const float* __restrict__ bb01,
    const float* __restrict__ wb11, const float* __restrict__ bb11,
    float* __restrict__ ws) {
  __shared__ __align__(16) float sW1a[64], sW1b[64], sc1[64], sc2[64];
  __shared__ __align__(16) float sW2T[2048];
  __shared__ __align__(16) float sPB01[1024], sPB11[3072];
  __shared__ __align__(16) float sBB01[32], sBB11[96];
  int tid = threadIdx.x;
  if (tid < 64) {
    sW1a[tid] = ws[OFF_FW1A + 128 + tid];
    sW1b[tid] = ws[OFF_FW1B + 128 + tid];
    sc1[tid] = ws[OFF_FC1 + 128 + tid];
    sc2[tid] = ws[OFF_FC2 + 128 + tid];
  }
  for (int t = tid; t < 2048; t += 256) sW2T[t] = ws[OFF_FW2T + 4096 + t];
  for (int t = tid; t < 1024; t += 256) {
    int i = t >> 5, c = t & 31;
    sPB01[c * 32 + i] = wb01[t];
  }
  for (int t = tid; t < 3072; t += 256) {
    int i = t / 96, c = t - i * 96;
    sPB11[c * 32 + i] = wb11[t];
  }
  if (tid < 32) sBB01[tid] = bb01[tid];
  if (tid < 96) sBB11[tid] = bb11[tid];
  __syncthreads();

  const float4* ec = (const float4*)(ws + OFF_ECACHE);
  float* outacc = ws + OFF_OUTACC;
  for (int e = blockIdx.x * blockDim.x + tid; e < NE;
       e += gridDim.x * blockDim.x) {
    int s = src[e], d = dst[e];
    float4 E4 = ec[e];
    float r = E4.x, ux = E4.y, uy = E4.z, uz = E4.w;
    float we = w[e];
    float y10 = Y1C * uy, y11 = Y1C * uz, y12 = Y1C * ux;
    float y20 = Y2C1 * ux * uy, y21 = Y2C1 * uy * uz;
    float y22 = Y2C2 * (3.0f * uz * uz - 1.0f);
    float y23 = Y2C1 * ux * uz, y24 = Y2C3 * (ux * ux - uy * uy);
    float S00 = -S6C * y22 - S2C * y24;
    float S11 = 2.0f * S6C * y22;
    float S22 = -S6C * y22 + S2C * y24;
    float S01 = S2C * y21, S02 = S2C * y20, S12 = S2C * y23;

    float H[MID];
    // net 4: A[o] = sum_ci Rb01[o,ci] * h0n[src,ci]
    mlpH_lds(sW1a, sW1b, sc1, sc2, sW2T, we, r, H);
    const float* h0p = ws + OFF_H0N + s * CDIM;
    float A0 = 0.0f, A1 = 0.0f;
#pragma unroll
    for (int ci = 0; ci < CDIM; ++ci) {
      float t0 = h0p[ci];
      float R0 = sBB01[ci];
      float R1 = sBB01[CDIM + ci];
#pragma unroll
      for (int i = 0; i < MID; ++i) {
        float hi = H[i];
        R0 = fmaf(hi, sPB01[ci * 32 + i], R0);
        R1 = fmaf(hi, sPB01[(CDIM + ci) * 32 + i], R1);
      }
      A0 = fmaf(R0, t0, A0);
      A1 = fmaf(R1, t0, A1);
    }
    // net 5: G[o][f][b] = sum_ci Rb11[o,ci,f] * h1n[src,ci,b]
    mlpH_lds(sW1a + 32, sW1b + 32, sc1 + 32, sc2 + 32, sW2T + 1024, we, r, H);
    const float* h1p = ws + OFF_H1N + s * CDIM * 3;
    float G[2][3][3];
#pragma unroll
    for (int o = 0; o < 2; ++o)
#pragma unroll
      for (int f = 0; f < 3; ++f) {
        G[o][f][0] = 0.0f; G[o][f][1] = 0.0f; G[o][f][2] = 0.0f;
      }
#pragma unroll
    for (int ci = 0; ci < CDIM; ++ci) {
      float t1b0 = h1p[ci * 3 + 0], t1b1 = h1p[ci * 3 + 1], t1b2 = h1p[ci * 3 + 2];
#pragma unroll
      for (int o = 0; o < 2; ++o) {
#pragma unroll
        for (int f = 0; f < 3; ++f) {
          float R = sBB11[o * 48 + ci * 3 + f];
#pragma unroll
          for (int i = 0; i < MID; ++i)
            R = fmaf(H[i], sPB11[(o * 48 + ci * 3 + f) * 32 + i], R);
          G[o][f][0] = fmaf(R, t1b0, G[o][f][0]);
          G[o][f][1] = fmaf(R, t1b1, G[o][f][1]);
          G[o][f][2] = fmaf(R, t1b2, G[o][f][2]);
        }
      }
    }
    float* op = outacc + d * 6;
#pragma unroll
    for (int o = 0; o < 2; ++o) {
      float Ao = (o == 0) ? A0 : A1;
      float mB0 = Ao * y10 + K0C * G[o][0][0]
                + S2C * (y12 * G[o][1][1] - y11 * G[o][1][2])
                + S00 * G[o][2][0] + S01 * G[o][2][1] + S02 * G[o][2][2];
      float mB1 = Ao * y11 + K0C * G[o][0][1]
                + S2C * (y10 * G[o][1][2] - y12 * G[o][1][0])
                + S01 * G[o][2][0] + S11 * G[o][2][1] + S12 * G[o][2][2];
      float mB2 = Ao * y12 + K0C * G[o][0][2]
                + S2C * (y11 * G[o][1][0] - y10 * G[o][1][1])
                + S02 * G[o][2][0] + S12 * G[o][2][1] + S22 * G[o][2][2];
      atomAddF(op + o * 3 + 0, mB0);
      atomAddF(op + o * 3 + 1, mB1);
      atomAddF(op + o * 3 + 2, mB2);
    }
  }
}

// ---- node update B: final output ----
__global__ __launch_bounds__(256) void k_nodeB(
    const float* __restrict__ selfB1, float* __restrict__ out,
    const float* __restrict__ ws) {
  int idx = blockIdx.x * blockDim.x + threadIdx.x;
  if (idx >= NN * 6) return;
  int n = idx / 6;
  int rem = idx - n * 6;
  int o = rem / 3, a = rem - o * 3;
  float dg = ws[OFF_DEG + n];
  float iv = 1.0f / fmaxf(dg, 1.0f);
  float mk = dg > 0.0f ? 1.0f : 0.0f;
  const float* h1p = ws + OFF_H1N + n * CDIM * 3;
  float self = 0.0f;
#pragma unroll
  for (int ci = 0; ci < CDIM; ++ci)
    self = fmaf(selfB1[o * CDIM + ci], h1p[ci * 3 + a], self);
  out[idx] = ws[OFF_OUTACC + idx] * iv + self * mk;
}

extern "C" void kernel_launch(void* const* d_in, const int* in_sizes, int n_in,
                              void* d_out, int out_size, void* d_ws, size_t ws_size,
                              hipStream_t stream) {
  (void)in_sizes; (void)n_in; (void)out_size; (void)ws_size;
  const int* src = (const int*)d_in[0];
  const int* dst = (const int*)d_in[1];
  const float* pos = (const float*)d_in[2];
  const float* cI = (const float*)d_in[3];
  const float* vI = (const float*)d_in[4];
  const float* w = (const float*)d_in[5];
  const float* rW1 = (const float*)d_in[6];
  const float* rb1 = (const float*)d_in[7];
  const float* rg1 = (const float*)d_in[8];
  const float* rbe1 = (const float*)d_in[9];
  const float* rW2 = (const float*)d_in[10];
  const float* rb2 = (const float*)d_in[11];
  const float* rg2 = (const float*)d_in[12];
  const float* rbe2 = (const float*)d_in[13];
  const float* w3_a00 = (const float*)d_in[14];
  const float* b3_a00 = (const float*)d_in[15];
  const float* w3_a01 = (const float*)d_in[16];
  const float* b3_a01 = (const float*)d_in[17];
  const float* w3_a10 = (const float*)d_in[18];
  const float* b3_a10 = (const float*)d_in[19];
  const float* w3_a11 = (const float*)d_in[20];
  const float* b3_a11 = (const float*)d_in[21];
  const float* w3_b01 = (const float*)d_in[22];
  const float* b3_b01 = (const float*)d_in[23];
  const float* w3_b11 = (const float*)d_in[24];
  const float* b3_b11 = (const float*)d_in[25];
  const float* selfA0 = (const float*)d_in[26];
  const float* selfA1 = (const float*)d_in[27];
  const float* selfB1 = (const float*)d_in[28];
  const float* nbias0 = (const float*)d_in[29];
  const float* nbias1 = (const float*)d_in[30];
  float* ws = (float*)d_ws;
  float* out = (float*)d_out;

  hipMemsetAsync(d_ws, 0, (size_t)ZERO_FLOATS * sizeof(float), stream);

  k_pass1<<<1250, 256, 0, stream>>>(src, dst, pos, w, ws);
  k_fin1<<<1, 192, 0, stream>>>(rW1, rb1, rg1, rbe1, ws);
  k_stats2<<<dim3(128, 6), 256, 0, stream>>>(w, rW2, rb2, ws);
  k_fin2<<<1, 192, 0, stream>>>(rb2, rg2, rbe2, ws);
  k_fold2<<<24, 256, 0, stream>>>(rW2, ws);
  k_passA<<<1250, 256, 0, stream>>>(src, dst, cI, vI, w,
                                    w3_a00, b3_a00, w3_a01, b3_a01,
                                    w3_a10, b3_a10, w3_a11, b3_a11, ws);
  k_nodeA<<<1250, 256, 0, stream>>>(cI, vI, selfA0, selfA1, nbias0, nbias1, ws);
  k_passB<<<1250, 256, 0, stream>>>(src, dst, w,
                                    w3_b01, b3_b01, w3_b11, b3_b11, ws);
  k_nodeB<<<469, 256, 0, stream>>>(selfB1, out, ws);
}

// Round 4
// 2152.951 us; speedup vs baseline: 2.6421x; 2.6421x over previous
//
#include <hip/hip_runtime.h>

#define NN 20000
#define NE 320000
#define CDIM 16
#define MID 32
#define EPSF 1e-8f

// ---- workspace float offsets ----
#define OFF_STATS1 0           //   8
#define OFF_STATS2 8           // 384  ([k][{sum,sq}][j])
#define OFF_DEG    392         // 20000
#define OFF_AGG0   20392       // 320000
#define OFF_AGG1   340392      // 960000
#define OFF_OUTACC 1300392     // 120000
#define ZERO_FLOATS 1420392
#define OFF_FW1A   1420392     // 192  (6*32)  W1[0]*a1
#define OFF_FW1B   1420584     // 192  W1[1]*a1
#define OFF_FC1    1420776     // 192  folded layer1 const
#define OFF_BN2A   1420968     // 192  a2
#define OFF_FC2    1421160     // 192  folded layer2 const
#define OFF_FW2T   1421352     // 6144 ([k][j][i] = W2[k][i][j]*a2[k][j])
#define OFF_ECACHE 1427496     // E*4 (float4: r,ux,uy,uz)
#define OFF_H0N    2707496     // 320000
#define OFF_H1N    3027496     // 960000
// total = 3987496 floats ~ 16.0 MB

// spherical-harmonic constants
#define Y0C   0.28209479177387814f
#define Y1C   0.4886025119029199f
#define Y2C1  1.0925484305920792f
#define Y2C2  0.31539156525252005f
#define Y2C3  0.5462742152960396f
#define S2C   0.7071067811865476f
#define S6C   0.4082482904638631f
#define K0C   0.16286750396763996f   // Y0/sqrt(3)

__device__ __forceinline__ void atomAddF(float* p, float v) {
  unsafeAtomicAdd(p, v);   // HW global_atomic_add_f32 on gfx950
}

// Folded 2-layer MLP, all weights in LDS (broadcast reads, b128-vectorized).
__device__ __forceinline__ void mlpH_lds(
    const float* __restrict__ a1, const float* __restrict__ b1v,
    const float* __restrict__ c1, const float* __restrict__ c2,
    const float* __restrict__ W2T, float we, float r, float* H) {
  float h[MID];
#pragma unroll
  for (int j = 0; j < MID; ++j)
    h[j] = fmaxf(fmaf(we, a1[j], fmaf(r, b1v[j], c1[j])), 0.0f);
#pragma unroll
  for (int j = 0; j < MID; ++j) {
    float acc = c2[j];
#pragma unroll
    for (int i = 0; i < MID; ++i) acc = fmaf(h[i], W2T[j * MID + i], acc);
    H[j] = fmaxf(acc, 0.0f);
  }
}

// ---- pass 1: edge geometry cache, degree, layer-1 stat scalars ----
__global__ __launch_bounds__(256) void k_pass1(
    const int* __restrict__ src, const int* __restrict__ dst,
    const float* __restrict__ pos, const float* __restrict__ w,
    float* __restrict__ ws) {
  float lw = 0, lr = 0, lww = 0, lrr = 0, lwr = 0;
  float* deg = ws + OFF_DEG;
  float4* ec = (float4*)(ws + OFF_ECACHE);
  for (int e = blockIdx.x * blockDim.x + threadIdx.x; e < NE;
       e += gridDim.x * blockDim.x) {
    int s = src[e], d = dst[e];
    float dx = pos[3 * d + 0] - pos[3 * s + 0];
    float dy = pos[3 * d + 1] - pos[3 * s + 1];
    float dz = pos[3 * d + 2] - pos[3 * s + 2];
    float r = sqrtf(dx * dx + dy * dy + dz * dz);
    float ri = 1.0f / fmaxf(r, EPSF);
    ec[e] = make_float4(r, dx * ri, dy * ri, dz * ri);
    float we = w[e];
    lw += we; lr += r; lww += we * we; lrr += r * r; lwr += we * r;
    atomAddF(deg + d, 1.0f);
  }
#pragma unroll
  for (int d = 32; d >= 1; d >>= 1) {
    lw += __shfl_xor(lw, d);
    lr += __shfl_xor(lr, d);
    lww += __shfl_xor(lww, d);
    lrr += __shfl_xor(lrr, d);
    lwr += __shfl_xor(lwr, d);
  }
  if ((threadIdx.x & 63) == 0) {
    atomAddF(ws + OFF_STATS1 + 0, lw);
    atomAddF(ws + OFF_STATS1 + 1, lr);
    atomAddF(ws + OFF_STATS1 + 2, lww);
    atomAddF(ws + OFF_STATS1 + 3, lrr);
    atomAddF(ws + OFF_STATS1 + 4, lwr);
  }
}

// ---- finalize BN layer 1 (analytic) -> folded layer1 weights ----
__global__ void k_fin1(const float* __restrict__ rW1, const float* __restrict__ rb1,
                       const float* __restrict__ rg1, const float* __restrict__ rbe1,
                       float* __restrict__ ws) {
  int t = threadIdx.x;  // 0..191
  int k = t >> 5, j = t & 31;
  float Sw = ws[OFF_STATS1 + 0], Sr = ws[OFF_STATS1 + 1];
  float Sww = ws[OFF_STATS1 + 2], Srr = ws[OFF_STATS1 + 3], Swr = ws[OFF_STATS1 + 4];
  const float inv = 1.0f / (float)NE;
  float W0 = rW1[k * 64 + j], W1 = rW1[k * 64 + 32 + j], b = rb1[k * 32 + j];
  float mlin = (Sw * W0 + Sr * W1) * inv;
  float mu = mlin + b;
  float ex2 = (Sww * W0 * W0 + Srr * W1 * W1 + 2.0f * Swr * W0 * W1) * inv
            + 2.0f * b * mlin + b * b;
  float var = ex2 - mu * mu;
  float a = rg1[k * 32 + j] * rsqrtf(var + 1e-5f);
  ws[OFF_FW1A + t] = W0 * a;
  ws[OFF_FW1B + t] = W1 * a;
  ws[OFF_FC1 + t] = rbe1[k * 32 + j] - mlin * a;   // = be + (b-mu)*a
}

// ---- pass 2: layer-2 pre-activation stats ----
// grid (Nb, 6, 4): network k = blockIdx.y, output chunk j0 = 8*blockIdx.z.
// Only 16 accumulator VGPRs live across the edge loop -> no spill.
__global__ __launch_bounds__(256) void k_stats2(
    const float* __restrict__ w,
    const float* __restrict__ rW2, const float* __restrict__ rb2,
    float* __restrict__ ws) {
  const int k = blockIdx.y;
  const int j0 = blockIdx.z * 8;
  __shared__ __align__(16) float sW1a[32], sW1b[32], sc1[32];
  __shared__ __align__(16) float sW2c[256];  // [jj][i]
  __shared__ float sb2[8];
  int tid = threadIdx.x;
  if (tid < 32) {
    sW1a[tid] = ws[OFF_FW1A + k * 32 + tid];
    sW1b[tid] = ws[OFF_FW1B + k * 32 + tid];
    sc1[tid] = ws[OFF_FC1 + k * 32 + tid];
  }
  if (tid < 8) sb2[tid] = rb2[k * 32 + j0 + tid];
  {
    int jj = tid >> 5, i = tid & 31;
    sW2c[tid] = rW2[k * 1024 + i * 32 + j0 + jj];
  }
  __syncthreads();
  const float4* ec = (const float4*)(ws + OFF_ECACHE);
  float lsum[8], lsq[8];
#pragma unroll
  for (int jj = 0; jj < 8; ++jj) { lsum[jj] = 0.0f; lsq[jj] = 0.0f; }
  for (int e = blockIdx.x * blockDim.x + tid; e < NE;
       e += gridDim.x * blockDim.x) {
    float r = ec[e].x;
    float we = w[e];
    float h[MID];
#pragma unroll
    for (int j = 0; j < MID; ++j)
      h[j] = fmaxf(fmaf(we, sW1a[j], fmaf(r, sW1b[j], sc1[j])), 0.0f);
#pragma unroll
    for (int jj = 0; jj < 8; ++jj) {
      float acc = sb2[jj];
#pragma unroll
      for (int i = 0; i < MID; ++i) acc = fmaf(h[i], sW2c[jj * 32 + i], acc);
      lsum[jj] += acc;
      lsq[jj] = fmaf(acc, acc, lsq[jj]);
    }
  }
#pragma unroll
  for (int jj = 0; jj < 8; ++jj) {
    float v1 = lsum[jj], v2 = lsq[jj];
#pragma unroll
    for (int d = 32; d >= 1; d >>= 1) {
      v1 += __shfl_xor(v1, d);
      v2 += __shfl_xor(v2, d);
    }
    if ((tid & 63) == 0) {
      atomAddF(ws + OFF_STATS2 + k * 64 + j0 + jj, v1);
      atomAddF(ws + OFF_STATS2 + k * 64 + 32 + j0 + jj, v2);
    }
  }
}

// ---- finalize BN layer 2 ----
__global__ void k_fin2(const float* __restrict__ rb2,
                       const float* __restrict__ rg2, const float* __restrict__ rbe2,
                       float* __restrict__ ws) {
  int t = threadIdx.x;  // 0..191
  int k = t >> 5, j = t & 31;
  const float inv = 1.0f / (float)NE;
  float mu = ws[OFF_STATS2 + k * 64 + j] * inv;
  float ex2 = ws[OFF_STATS2 + k * 64 + 32 + j] * inv;
  float var = ex2 - mu * mu;
  float a = rg2[t] * rsqrtf(var + 1e-5f);
  ws[OFF_BN2A + t] = a;
  ws[OFF_FC2 + t] = rbe2[t] + (rb2[t] - mu) * a;
}

// ---- fold a2 into W2, transposed: fW2T[k][j][i] = W2[k][i][j]*a2[k][j] ----
__global__ __launch_bounds__(256) void k_fold2(const float* __restrict__ rW2,
                                               float* __restrict__ ws) {
  int idx = blockIdx.x * blockDim.x + threadIdx.x;  // 0..6143
  if (idx >= 6144) return;
  int k = idx >> 10, rem = idx & 1023;
  int j = rem >> 5, i = rem & 31;
  ws[OFF_FW2T + idx] = rW2[k * 1024 + i * 32 + j] * ws[OFF_BN2A + k * 32 + j];
}

// ---- stage A: per-edge messages m0 (C), m1 (C,3) -> atomic scatter ----
__global__ __launch_bounds__(256) void k_passA(
    const int* __restrict__ src, const int* __restrict__ dst,
    const float* __restrict__ cI, const float* __restrict__ vI,
    const float* __restrict__ w,
    const float* __restrict__ w00, const float* __restrict__ b00,
    const float* __restrict__ w01, const float* __restrict__ b01,
    const float* __restrict__ w10, const float* __restrict__ b10,
    const float* __restrict__ w11, const float* __restrict__ b11,
    float* __restrict__ ws) {
  __shared__ __align__(16) float sW1a[128], sW1b[128], sc1[128], sc2[128];
  __shared__ __align__(16) float sW2T[4096];
  __shared__ __align__(16) float sP00[512], sP01[512], sP10[512], sP11[1536];
  __shared__ __align__(16) float sB00[16], sB01[16], sB10[16], sB11[48];
  int tid = threadIdx.x;
  if (tid < 128) {
    sW1a[tid] = ws[OFF_FW1A + tid];
    sW1b[tid] = ws[OFF_FW1B + tid];
    sc1[tid] = ws[OFF_FC1 + tid];
    sc2[tid] = ws[OFF_FC2 + tid];
  }
  for (int t = tid; t < 4096; t += 256) sW2T[t] = ws[OFF_FW2T + t];
  for (int t = tid; t < 512; t += 256) {
    int i = t >> 4, co = t & 15;
    sP00[co * 32 + i] = w00[t];
    sP01[co * 32 + i] = w01[t];
    sP10[co * 32 + i] = w10[t];
  }
  for (int t = tid; t < 1536; t += 256) {
    int i = t / 48, c = t - i * 48;
    sP11[c * 32 + i] = w11[t];
  }
  if (tid < 16) { sB00[tid] = b00[tid]; sB01[tid] = b01[tid]; sB10[tid] = b10[tid]; }
  if (tid < 48) sB11[tid] = b11[tid];
  __syncthreads();

  const float4* ec = (const float4*)(ws + OFF_ECACHE);
  float* agg0 = ws + OFF_AGG0;
  float* agg1 = ws + OFF_AGG1;
  for (int e = blockIdx.x * blockDim.x + tid; e < NE;
       e += gridDim.x * blockDim.x) {
    int s = src[e], d = dst[e];
    float4 E4 = ec[e];
    float r = E4.x, ux = E4.y, uy = E4.z, uz = E4.w;
    float we = w[e];
    float cs = cI[s];
    float v0 = vI[3 * s + 0], v1 = vI[3 * s + 1], v2 = vI[3 * s + 2];
    float y10 = Y1C * uy, y11 = Y1C * uz, y12 = Y1C * ux;
    float y20 = Y2C1 * ux * uy, y21 = Y2C1 * uy * uz;
    float y22 = Y2C2 * (3.0f * uz * uz - 1.0f);
    float y23 = Y2C1 * ux * uz, y24 = Y2C3 * (ux * ux - uy * uy);
    float S00 = -S6C * y22 - S2C * y24;
    float S11 = 2.0f * S6C * y22;
    float S22 = -S6C * y22 + S2C * y24;
    float S01 = S2C * y21, S02 = S2C * y20, S12 = S2C * y23;
    float KV[3][3];
    KV[0][0] = K0C * v0; KV[0][1] = K0C * v1; KV[0][2] = K0C * v2;
    KV[1][0] = S2C * (y12 * v1 - y11 * v2);
    KV[1][1] = S2C * (y10 * v2 - y12 * v0);
    KV[1][2] = S2C * (y11 * v0 - y10 * v1);
    KV[2][0] = S00 * v0 + S01 * v1 + S02 * v2;
    KV[2][1] = S01 * v0 + S11 * v1 + S12 * v2;
    KV[2][2] = S02 * v0 + S12 * v1 + S22 * v2;
    float dY1v = y10 * v0 + y11 * v1 + y12 * v2;

    float H[MID];
    float m0[CDIM], m1[CDIM * 3];

    // net 0: m0 = R00 * Y0 * c_src
    mlpH_lds(sW1a, sW1b, sc1, sc2, sW2T, we, r, H);
    float f0 = Y0C * cs;
#pragma unroll
    for (int co = 0; co < CDIM; ++co) {
      float acc = sB00[co];
#pragma unroll
      for (int i = 0; i < MID; ++i) acc = fmaf(H[i], sP00[co * 32 + i], acc);
      m0[co] = acc * f0;
    }
    // net 2: m0 += R10 * (Y1 . v_src)
    mlpH_lds(sW1a + 64, sW1b + 64, sc1 + 64, sc2 + 64, sW2T + 2048, we, r, H);
#pragma unroll
    for (int co = 0; co < CDIM; ++co) {
      float acc = sB10[co];
#pragma unroll
      for (int i = 0; i < MID; ++i) acc = fmaf(H[i], sP10[co * 32 + i], acc);
      m0[co] = fmaf(acc, dY1v, m0[co]);
    }
    // net 1: m1 = R01 * c_src * Y1[a]
    mlpH_lds(sW1a + 32, sW1b + 32, sc1 + 32, sc2 + 32, sW2T + 1024, we, r, H);
    float cy0 = cs * y10, cy1 = cs * y11, cy2 = cs * y12;
#pragma unroll
    for (int co = 0; co < CDIM; ++co) {
      float acc = sB01[co];
#pragma unroll
      for (int i = 0; i < MID; ++i) acc = fmaf(H[i], sP01[co * 32 + i], acc);
      m1[co * 3 + 0] = acc * cy0;
      m1[co * 3 + 1] = acc * cy1;
      m1[co * 3 + 2] = acc * cy2;
    }
    // net 3: m1[co][a] += sum_f R11[co,f] * KV[f][a]
    mlpH_lds(sW1a + 96, sW1b + 96, sc1 + 96, sc2 + 96, sW2T + 3072, we, r, H);
#pragma unroll
    for (int co = 0; co < CDIM; ++co) {
#pragma unroll
      for (int f = 0; f < 3; ++f) {
        float acc = sB11[co * 3 + f];
#pragma unroll
        for (int i = 0; i < MID; ++i)
          acc = fmaf(H[i], sP11[(co * 3 + f) * 32 + i], acc);
        m1[co * 3 + 0] = fmaf(acc, KV[f][0], m1[co * 3 + 0]);
        m1[co * 3 + 1] = fmaf(acc, KV[f][1], m1[co * 3 + 1]);
        m1[co * 3 + 2] = fmaf(acc, KV[f][2], m1[co * 3 + 2]);
      }
    }
    float* p0 = agg0 + d * CDIM;
    float* p1 = agg1 + d * CDIM * 3;
#pragma unroll
    for (int co = 0; co < CDIM; ++co) atomAddF(p0 + co, m0[co]);
#pragma unroll
    for (int q = 0; q < CDIM * 3; ++q) atomAddF(p1 + q, m1[q]);
  }
}

// ---- node update A: normalize aggregates, norm_bias -> h0n, h1n ----
__global__ __launch_bounds__(256) void k_nodeA(
    const float* __restrict__ cI, const float* __restrict__ vI,
    const float* __restrict__ selfA0, const float* __restrict__ selfA1,
    const float* __restrict__ nbias0, const float* __restrict__ nbias1,
    float* __restrict__ ws) {
  int idx = blockIdx.x * blockDim.x + threadIdx.x;
  if (idx >= NN * CDIM) return;
  int n = idx >> 4, co = idx & 15;
  float dg = ws[OFF_DEG + n];
  float iv = 1.0f / fmaxf(dg, 1.0f);
  float mk = dg > 0.0f ? 1.0f : 0.0f;
  float x0 = ws[OFF_AGG0 + idx] * iv + selfA0[co] * cI[n] * mk;
  float n0 = sqrtf(x0 * x0 + 1e-12f);
  ws[OFF_H0N + idx] = fmaxf(n0 + nbias0[co], 0.0f) * (x0 / fmaxf(n0, EPSF));
  float xa = ws[OFF_AGG1 + idx * 3 + 0] * iv + selfA1[co] * vI[3 * n + 0] * mk;
  float xb = ws[OFF_AGG1 + idx * 3 + 1] * iv + selfA1[co] * vI[3 * n + 1] * mk;
  float xc = ws[OFF_AGG1 + idx * 3 + 2] * iv + selfA1[co] * vI[3 * n + 2] * mk;
  float nv = sqrtf(xa * xa + xb * xb + xc * xc + 1e-12f);
  float sc = fmaxf(nv + nbias1[co], 0.0f) / fmaxf(nv, EPSF);
  ws[OFF_H1N + idx * 3 + 0] = xa * sc;
  ws[OFF_H1N + idx * 3 + 1] = xb * sc;
  ws[OFF_H1N + idx * 3 + 2] = xc * sc;
}

// ---- stage B: per-edge output messages -> atomic scatter ----
__global__ __launch_bounds__(256) void k_passB(
    const int* __restrict__ src, const int* __restrict__ dst,
    const float* __restrict__ w,
    const float* __restrict__ wb01, const float* __restrict__ bb01,
    const float* __restrict__ wb11, const float* __restrict__ bb11,
    float* __restrict__ ws) {
  __shared__ __align__(16) float sW1a[64], sW1b[64], sc1[64], sc2[64];
  __shared__ __align__(16) float sW2T[2048];
  __shared__ __align__(16) float sPB01[1024], sPB11[3072];
  __shared__ __align__(16) float sBB01[32], sBB11[96];
  int tid = threadIdx.x;
  if (tid < 64) {
    sW1a[tid] = ws[OFF_FW1A + 128 + tid];
    sW1b[tid] = ws[OFF_FW1B + 128 + tid];
    sc1[tid] = ws[OFF_FC1 + 128 + tid];
    sc2[tid] = ws[OFF_FC2 + 128 + tid];
  }
  for (int t = tid; t < 2048; t += 256) sW2T[t] = ws[OFF_FW2T + 4096 + t];
  for (int t = tid; t < 1024; t += 256) {
    int i = t >> 5, c = t & 31;
    sPB01[c * 32 + i] = wb01[t];
  }
  for (int t = tid; t < 3072; t += 256) {
    int i = t / 96, c = t - i * 96;
    sPB11[c * 32 + i] = wb11[t];
  }
  if (tid < 32) sBB01[tid] = bb01[tid];
  if (tid < 96) sBB11[tid] = bb11[tid];
  __syncthreads();

  const float4* ec = (const float4*)(ws + OFF_ECACHE);
  float* outacc = ws + OFF_OUTACC;
  for (int e = blockIdx.x * blockDim.x + tid; e < NE;
       e += gridDim.x * blockDim.x) {
    int s = src[e], d = dst[e];
    float4 E4 = ec[e];
    float r = E4.x, ux = E4.y, uy = E4.z, uz = E4.w;
    float we = w[e];
    float y10 = Y1C * uy, y11 = Y1C * uz, y12 = Y1C * ux;
    float y20 = Y2C1 * ux * uy, y21 = Y2C1 * uy * uz;
    float y22 = Y2C2 * (3.0f * uz * uz - 1.0f);
    float y23 = Y2C1 * ux * uz, y24 = Y2C3 * (ux * ux - uy * uy);
    float S00 = -S6C * y22 - S2C * y24;
    float S11 = 2.0f * S6C * y22;
    float S22 = -S6C * y22 + S2C * y24;
    float S01 = S2C * y21, S02 = S2C * y20, S12 = S2C * y23;

    float H[MID];
    // net 4: A[o] = sum_ci Rb01[o,ci] * h0n[src,ci]
    mlpH_lds(sW1a, sW1b, sc1, sc2, sW2T, we, r, H);
    const float* h0p = ws + OFF_H0N + s * CDIM;
    float A0 = 0.0f, A1 = 0.0f;
#pragma unroll
    for (int ci = 0; ci < CDIM; ++ci) {
      float t0 = h0p[ci];
      float R0 = sBB01[ci];
      float R1 = sBB01[CDIM + ci];
#pragma unroll
      for (int i = 0; i < MID; ++i) {
        float hi = H[i];
        R0 = fmaf(hi, sPB01[ci * 32 + i], R0);
        R1 = fmaf(hi, sPB01[(CDIM + ci) * 32 + i], R1);
      }
      A0 = fmaf(R0, t0, A0);
      A1 = fmaf(R1, t0, A1);
    }
    // net 5: G[o][f][b] = sum_ci Rb11[o,ci,f] * h1n[src,ci,b]
    mlpH_lds(sW1a + 32, sW1b + 32, sc1 + 32, sc2 + 32, sW2T + 1024, we, r, H);
    const float* h1p = ws + OFF_H1N + s * CDIM * 3;
    float G[2][3][3];
#pragma unroll
    for (int o = 0; o < 2; ++o)
#pragma unroll
      for (int f = 0; f < 3; ++f) {
        G[o][f][0] = 0.0f; G[o][f][1] = 0.0f; G[o][f][2] = 0.0f;
      }
#pragma unroll
    for (int ci = 0; ci < CDIM; ++ci) {
      float t1b0 = h1p[ci * 3 + 0], t1b1 = h1p[ci * 3 + 1], t1b2 = h1p[ci * 3 + 2];
#pragma unroll
      for (int o = 0; o < 2; ++o) {
#pragma unroll
        for (int f = 0; f < 3; ++f) {
          float R = sBB11[o * 48 + ci * 3 + f];
#pragma unroll
          for (int i = 0; i < MID; ++i)
            R = fmaf(H[i], sPB11[(o * 48 + ci * 3 + f) * 32 + i], R);
          G[o][f][0] = fmaf(R, t1b0, G[o][f][0]);
          G[o][f][1] = fmaf(R, t1b1, G[o][f][1]);
          G[o][f][2] = fmaf(R, t1b2, G[o][f][2]);
        }
      }
    }
    float* op = outacc + d * 6;
#pragma unroll
    for (int o = 0; o < 2; ++o) {
      float Ao = (o == 0) ? A0 : A1;
      float mB0 = Ao * y10 + K0C * G[o][0][0]
                + S2C * (y12 * G[o][1][1] - y11 * G[o][1][2])
                + S00 * G[o][2][0] + S01 * G[o][2][1] + S02 * G[o][2][2];
      float mB1 = Ao * y11 + K0C * G[o][0][1]
                + S2C * (y10 * G[o][1][2] - y12 * G[o][1][0])
                + S01 * G[o][2][0] + S11 * G[o][2][1] + S12 * G[o][2][2];
      float mB2 = Ao * y12 + K0C * G[o][0][2]
                + S2C * (y11 * G[o][1][0] - y10 * G[o][1][1])
                + S02 * G[o][2][0] + S12 * G[o][2][1] + S22 * G[o][2][2];
      atomAddF(op + o * 3 + 0, mB0);
      atomAddF(op + o * 3 + 1, mB1);
      atomAddF(op + o * 3 + 2, mB2);
    }
  }
}

// ---- node update B: final output ----
__global__ __launch_bounds__(256) void k_nodeB(
    const float* __restrict__ selfB1, float* __restrict__ out,
    const float* __restrict__ ws) {
  int idx = blockIdx.x * blockDim.x + threadIdx.x;
  if (idx >= NN * 6) return;
  int n = idx / 6;
  int rem = idx - n * 6;
  int o = rem / 3, a = rem - o * 3;
  float dg = ws[OFF_DEG + n];
  float iv = 1.0f / fmaxf(dg, 1.0f);
  float mk = dg > 0.0f ? 1.0f : 0.0f;
  const float* h1p = ws + OFF_H1N + n * CDIM * 3;
  float self = 0.0f;
#pragma unroll
  for (int ci = 0; ci < CDIM; ++ci)
    self = fmaf(selfB1[o * CDIM + ci], h1p[ci * 3 + a], self);
  out[idx] = ws[OFF_OUTACC + idx] * iv + self * mk;
}

extern "C" void kernel_launch(void* const* d_in, const int* in_sizes, int n_in,
                              void* d_out, int out_size, void* d_ws, size_t ws_size,
                              hipStream_t stream) {
  (void)in_sizes; (void)n_in; (void)out_size; (void)ws_size;
  const int* src = (const int*)d_in[0];
  const int* dst = (const int*)d_in[1];
  const float* pos = (const float*)d_in[2];
  const float* cI = (const float*)d_in[3];
  const float* vI = (const float*)d_in[4];
  const float* w = (const float*)d_in[5];
  const float* rW1 = (const float*)d_in[6];
  const float* rb1 = (const float*)d_in[7];
  const float* rg1 = (const float*)d_in[8];
  const float* rbe1 = (const float*)d_in[9];
  const float* rW2 = (const float*)d_in[10];
  const float* rb2 = (const float*)d_in[11];
  const float* rg2 = (const float*)d_in[12];
  const float* rbe2 = (const float*)d_in[13];
  const float* w3_a00 = (const float*)d_in[14];
  const float* b3_a00 = (const float*)d_in[15];
  const float* w3_a01 = (const float*)d_in[16];
  const float* b3_a01 = (const float*)d_in[17];
  const float* w3_a10 = (const float*)d_in[18];
  const float* b3_a10 = (const float*)d_in[19];
  const float* w3_a11 = (const float*)d_in[20];
  const float* b3_a11 = (const float*)d_in[21];
  const float* w3_b01 = (const float*)d_in[22];
  const float* b3_b01 = (const float*)d_in[23];
  const float* w3_b11 = (const float*)d_in[24];
  const float* b3_b11 = (const float*)d_in[25];
  const float* selfA0 = (const float*)d_in[26];
  const float* selfA1 = (const float*)d_in[27];
  const float* selfB1 = (const float*)d_in[28];
  const float* nbias0 = (const float*)d_in[29];
  const float* nbias1 = (const float*)d_in[30];
  float* ws = (float*)d_ws;
  float* out = (float*)d_out;

  hipMemsetAsync(d_ws, 0, (size_t)ZERO_FLOATS * sizeof(float), stream);

  k_pass1<<<1250, 256, 0, stream>>>(src, dst, pos, w, ws);
  k_fin1<<<1, 192, 0, stream>>>(rW1, rb1, rg1, rbe1, ws);
  k_stats2<<<dim3(64, 6, 4), 256, 0, stream>>>(w, rW2, rb2, ws);
  k_fin2<<<1, 192, 0, stream>>>(rb2, rg2, rbe2, ws);
  k_fold2<<<24, 256, 0, stream>>>(rW2, ws);
  k_passA<<<1250, 256, 0, stream>>>(src, dst, cI, vI, w,
                                    w3_a00, b3_a00, w3_a01, b3_a01,
                                    w3_a10, b3_a10, w3_a11, b3_a11, ws);
  k_nodeA<<<1250, 256, 0, stream>>>(cI, vI, selfA0, selfA1, nbias0, nbias1, ws);
  k_passB<<<1250, 256, 0, stream>>>(src, dst, w,
                                    w3_b01, b3_b01, w3_b11, b3_b11, ws);
  k_nodeB<<<469, 256, 0, stream>>>(selfB1, out, ws);
}

// Round 5
// 1562.146 us; speedup vs baseline: 3.6413x; 1.3782x over previous
//
#include <hip/hip_runtime.h>

#define NN 20000
#define NE 320000
#define CDIM 16
#define MID 32
#define EPSF 1e-8f

// ---- workspace word (4B) offsets ----
#define OFF_STATS1 0           //   8 f
#define OFF_STATS2 8           // 384 f
#define OFF_DEGI   392         // 20000 int (histogram)
#define ZERO_WORDS 20392
#define OFF_ROWPTR 20392       // 20001 int
#define OFF_CURSOR 40393       // 20000 int
#define OFF_EORDER 60393       // 320000 int
#define OFF_FW1A   380393      // 192
#define OFF_FW1B   380585      // 192
#define OFF_FC1    380777      // 192
#define OFF_BN2A   380969      // 192
#define OFF_FC2    381161      // 192
#define OFF_FW2T   381353      // 6144
#define OFF_ECACHE 387500      // 1280000 (float4: r,ux,uy,uz), 16B aligned
#define OFF_H0N    1667500     // 320000
#define OFF_H1N    1987500     // 960000
#define OFF_MSGA0  2947500     // 5120000  (16 f / edge, sorted order)
#define OFF_MSGA1  8067500     // 15360000 (48 f / edge)
#define OFF_MSGB   23427500    // 1920000  (6 f / edge)
// total 25347500 words ~ 101.4 MB

// spherical-harmonic constants
#define Y0C   0.28209479177387814f
#define Y1C   0.4886025119029199f
#define Y2C1  1.0925484305920792f
#define Y2C2  0.31539156525252005f
#define Y2C3  0.5462742152960396f
#define S2C   0.7071067811865476f
#define S6C   0.4082482904638631f
#define K0C   0.16286750396763996f   // Y0/sqrt(3)

__device__ __forceinline__ void atomAddF(float* p, float v) {
  unsafeAtomicAdd(p, v);
}

// Folded 2-layer MLP, weights in LDS (broadcast reads).
__device__ __forceinline__ void mlpH_lds(
    const float* __restrict__ a1, const float* __restrict__ b1v,
    const float* __restrict__ c1, const float* __restrict__ c2,
    const float* __restrict__ W2T, float we, float r, float* H) {
  float h[MID];
#pragma unroll
  for (int j = 0; j < MID; ++j)
    h[j] = fmaxf(fmaf(we, a1[j], fmaf(r, b1v[j], c1[j])), 0.0f);
#pragma unroll
  for (int j = 0; j < MID; ++j) {
    float acc = c2[j];
#pragma unroll
    for (int i = 0; i < MID; ++i) acc = fmaf(h[i], W2T[j * MID + i], acc);
    H[j] = fmaxf(acc, 0.0f);
  }
}

// ---- pass 1: edge geometry cache, int degree histogram, layer-1 stats ----
__global__ __launch_bounds__(256) void k_pass1(
    const int* __restrict__ src, const int* __restrict__ dst,
    const float* __restrict__ pos, const float* __restrict__ w,
    float* __restrict__ ws) {
  float lw = 0, lr = 0, lww = 0, lrr = 0, lwr = 0;
  int* degi = (int*)ws + OFF_DEGI;
  float4* ec = (float4*)(ws + OFF_ECACHE);
  for (int e = blockIdx.x * blockDim.x + threadIdx.x; e < NE;
       e += gridDim.x * blockDim.x) {
    int s = src[e], d = dst[e];
    float dx = pos[3 * d + 0] - pos[3 * s + 0];
    float dy = pos[3 * d + 1] - pos[3 * s + 1];
    float dz = pos[3 * d + 2] - pos[3 * s + 2];
    float r = sqrtf(dx * dx + dy * dy + dz * dz);
    float ri = 1.0f / fmaxf(r, EPSF);
    ec[e] = make_float4(r, dx * ri, dy * ri, dz * ri);
    float we = w[e];
    lw += we; lr += r; lww += we * we; lrr += r * r; lwr += we * r;
    atomicAdd(degi + d, 1);
  }
#pragma unroll
  for (int d = 32; d >= 1; d >>= 1) {
    lw += __shfl_xor(lw, d);
    lr += __shfl_xor(lr, d);
    lww += __shfl_xor(lww, d);
    lrr += __shfl_xor(lrr, d);
    lwr += __shfl_xor(lwr, d);
  }
  if ((threadIdx.x & 63) == 0) {
    atomAddF(ws + OFF_STATS1 + 0, lw);
    atomAddF(ws + OFF_STATS1 + 1, lr);
    atomAddF(ws + OFF_STATS1 + 2, lww);
    atomAddF(ws + OFF_STATS1 + 3, lrr);
    atomAddF(ws + OFF_STATS1 + 4, lwr);
  }
}

// ---- exclusive scan of degi -> rowptr, cursor (single block) ----
__global__ void k_scan(float* __restrict__ ws) {
  __shared__ int buf[256];
  __shared__ int carry;
  const int* degi = (const int*)ws + OFF_DEGI;
  int* rowptr = (int*)ws + OFF_ROWPTR;
  int* cursor = (int*)ws + OFF_CURSOR;
  int tid = threadIdx.x;
  if (tid == 0) carry = 0;
  __syncthreads();
  for (int base = 0; base < NN; base += 256) {
    int v = (base + tid < NN) ? degi[base + tid] : 0;
    buf[tid] = v;
    __syncthreads();
    for (int off = 1; off < 256; off <<= 1) {
      int t = buf[tid];
      int add = (tid >= off) ? buf[tid - off] : 0;
      __syncthreads();
      buf[tid] = t + add;
      __syncthreads();
    }
    int excl = buf[tid] - v;
    if (base + tid < NN) {
      rowptr[base + tid] = carry + excl;
      cursor[base + tid] = carry + excl;
    }
    __syncthreads();
    if (tid == 255) carry += buf[255];
    __syncthreads();
  }
  if (tid == 0) rowptr[NN] = carry;
}

// ---- scatter edge ids into dst-sorted order ----
__global__ __launch_bounds__(256) void k_scatter(
    const int* __restrict__ dst, float* __restrict__ ws) {
  int e = blockIdx.x * blockDim.x + threadIdx.x;
  if (e >= NE) return;
  int* cursor = (int*)ws + OFF_CURSOR;
  int* eorder = (int*)ws + OFF_EORDER;
  int d = dst[e];
  int p = atomicAdd(cursor + d, 1);
  eorder[p] = e;
}

// ---- finalize BN layer 1 (analytic) -> folded layer1 weights ----
__global__ void k_fin1(const float* __restrict__ rW1, const float* __restrict__ rb1,
                       const float* __restrict__ rg1, const float* __restrict__ rbe1,
                       float* __restrict__ ws) {
  int t = threadIdx.x;  // 0..191
  int k = t >> 5, j = t & 31;
  float Sw = ws[OFF_STATS1 + 0], Sr = ws[OFF_STATS1 + 1];
  float Sww = ws[OFF_STATS1 + 2], Srr = ws[OFF_STATS1 + 3], Swr = ws[OFF_STATS1 + 4];
  const float inv = 1.0f / (float)NE;
  float W0 = rW1[k * 64 + j], W1 = rW1[k * 64 + 32 + j], b = rb1[k * 32 + j];
  float mlin = (Sw * W0 + Sr * W1) * inv;
  float mu = mlin + b;
  float ex2 = (Sww * W0 * W0 + Srr * W1 * W1 + 2.0f * Swr * W0 * W1) * inv
            + 2.0f * b * mlin + b * b;
  float var = ex2 - mu * mu;
  float a = rg1[k * 32 + j] * rsqrtf(var + 1e-5f);
  ws[OFF_FW1A + t] = W0 * a;
  ws[OFF_FW1B + t] = W1 * a;
  ws[OFF_FC1 + t] = rbe1[k * 32 + j] - mlin * a;
}

// ---- layer-2 pre-activation stats (k = blockIdx.y, j-chunk = blockIdx.z) ----
__global__ __launch_bounds__(256) void k_stats2(
    const float* __restrict__ w,
    const float* __restrict__ rW2, const float* __restrict__ rb2,
    float* __restrict__ ws) {
  const int k = blockIdx.y;
  const int j0 = blockIdx.z * 8;
  __shared__ __align__(16) float sW1a[32], sW1b[32], sc1[32];
  __shared__ __align__(16) float sW2c[256];  // [jj][i]
  __shared__ float sb2[8];
  int tid = threadIdx.x;
  if (tid < 32) {
    sW1a[tid] = ws[OFF_FW1A + k * 32 + tid];
    sW1b[tid] = ws[OFF_FW1B + k * 32 + tid];
    sc1[tid] = ws[OFF_FC1 + k * 32 + tid];
  }
  if (tid < 8) sb2[tid] = rb2[k * 32 + j0 + tid];
  {
    int jj = tid >> 5, i = tid & 31;
    sW2c[tid] = rW2[k * 1024 + i * 32 + j0 + jj];
  }
  __syncthreads();
  const float4* ec = (const float4*)(ws + OFF_ECACHE);
  float lsum[8], lsq[8];
#pragma unroll
  for (int jj = 0; jj < 8; ++jj) { lsum[jj] = 0.0f; lsq[jj] = 0.0f; }
  for (int e = blockIdx.x * blockDim.x + tid; e < NE;
       e += gridDim.x * blockDim.x) {
    float r = ec[e].x;
    float we = w[e];
    float h[MID];
#pragma unroll
    for (int j = 0; j < MID; ++j)
      h[j] = fmaxf(fmaf(we, sW1a[j], fmaf(r, sW1b[j], sc1[j])), 0.0f);
#pragma unroll
    for (int jj = 0; jj < 8; ++jj) {
      float acc = sb2[jj];
#pragma unroll
      for (int i = 0; i < MID; ++i) acc = fmaf(h[i], sW2c[jj * 32 + i], acc);
      lsum[jj] += acc;
      lsq[jj] = fmaf(acc, acc, lsq[jj]);
    }
  }
#pragma unroll
  for (int jj = 0; jj < 8; ++jj) {
    float v1 = lsum[jj], v2 = lsq[jj];
#pragma unroll
    for (int d = 32; d >= 1; d >>= 1) {
      v1 += __shfl_xor(v1, d);
      v2 += __shfl_xor(v2, d);
    }
    if ((tid & 63) == 0) {
      atomAddF(ws + OFF_STATS2 + k * 64 + j0 + jj, v1);
      atomAddF(ws + OFF_STATS2 + k * 64 + 32 + j0 + jj, v2);
    }
  }
}

// ---- finalize BN layer 2 ----
__global__ void k_fin2(const float* __restrict__ rb2,
                       const float* __restrict__ rg2, const float* __restrict__ rbe2,
                       float* __restrict__ ws) {
  int t = threadIdx.x;  // 0..191
  int k = t >> 5, j = t & 31;
  const float inv = 1.0f / (float)NE;
  float mu = ws[OFF_STATS2 + k * 64 + j] * inv;
  float ex2 = ws[OFF_STATS2 + k * 64 + 32 + j] * inv;
  float var = ex2 - mu * mu;
  float a = rg2[t] * rsqrtf(var + 1e-5f);
  ws[OFF_BN2A + t] = a;
  ws[OFF_FC2 + t] = rbe2[t] + (rb2[t] - mu) * a;
}

// ---- fold a2 into W2, transposed ----
__global__ __launch_bounds__(256) void k_fold2(const float* __restrict__ rW2,
                                               float* __restrict__ ws) {
  int idx = blockIdx.x * blockDim.x + threadIdx.x;
  if (idx >= 6144) return;
  int k = idx >> 10, rem = idx & 1023;
  int j = rem >> 5, i = rem & 31;
  ws[OFF_FW2T + idx] = rW2[k * 1024 + i * 32 + j] * ws[OFF_BN2A + k * 32 + j];
}

// ---- stage A0: nets 0,2 -> m0[16] -> msgA0 (sorted, coalesced) ----
__global__ __launch_bounds__(256) void k_passA0(
    const int* __restrict__ src,
    const float* __restrict__ cI, const float* __restrict__ vI,
    const float* __restrict__ w,
    const float* __restrict__ w00, const float* __restrict__ b00,
    const float* __restrict__ w10, const float* __restrict__ b10,
    float* __restrict__ ws) {
  __shared__ __align__(16) float sW1a[64], sW1b[64], sc1[64], sc2[64];
  __shared__ __align__(16) float sW2T[2048];
  __shared__ __align__(16) float sP00[512], sP10[512];
  __shared__ float sB00[16], sB10[16];
  int tid = threadIdx.x;
  if (tid < 32) {
    sW1a[tid] = ws[OFF_FW1A + tid];       sW1a[32 + tid] = ws[OFF_FW1A + 64 + tid];
    sW1b[tid] = ws[OFF_FW1B + tid];       sW1b[32 + tid] = ws[OFF_FW1B + 64 + tid];
    sc1[tid]  = ws[OFF_FC1 + tid];        sc1[32 + tid]  = ws[OFF_FC1 + 64 + tid];
    sc2[tid]  = ws[OFF_FC2 + tid];        sc2[32 + tid]  = ws[OFF_FC2 + 64 + tid];
  }
  for (int t = tid; t < 1024; t += 256) {
    sW2T[t] = ws[OFF_FW2T + t];
    sW2T[1024 + t] = ws[OFF_FW2T + 2048 + t];
  }
  for (int t = tid; t < 512; t += 256) {
    int i = t >> 4, co = t & 15;
    sP00[co * 32 + i] = w00[t];
    sP10[co * 32 + i] = w10[t];
  }
  if (tid < 16) { sB00[tid] = b00[tid]; sB10[tid] = b10[tid]; }
  __syncthreads();

  const int* eorder = (const int*)ws + OFF_EORDER;
  const float4* ec = (const float4*)(ws + OFF_ECACHE);
  for (int t = blockIdx.x * blockDim.x + tid; t < NE;
       t += gridDim.x * blockDim.x) {
    int e = eorder[t];
    int s = src[e];
    float4 E4 = ec[e];
    float r = E4.x, ux = E4.y, uy = E4.z, uz = E4.w;
    float we = w[e];
    float cs = cI[s];
    float v0 = vI[3 * s + 0], v1 = vI[3 * s + 1], v2 = vI[3 * s + 2];
    float y10 = Y1C * uy, y11 = Y1C * uz, y12 = Y1C * ux;
    float dY1v = y10 * v0 + y11 * v1 + y12 * v2;
    float H[MID];
    float m0[CDIM];
    mlpH_lds(sW1a, sW1b, sc1, sc2, sW2T, we, r, H);
    float f0 = Y0C * cs;
#pragma unroll
    for (int co = 0; co < CDIM; ++co) {
      float acc = sB00[co];
#pragma unroll
      for (int i = 0; i < MID; ++i) acc = fmaf(H[i], sP00[co * 32 + i], acc);
      m0[co] = acc * f0;
    }
    mlpH_lds(sW1a + 32, sW1b + 32, sc1 + 32, sc2 + 32, sW2T + 1024, we, r, H);
#pragma unroll
    for (int co = 0; co < CDIM; ++co) {
      float acc = sB10[co];
#pragma unroll
      for (int i = 0; i < MID; ++i) acc = fmaf(H[i], sP10[co * 32 + i], acc);
      m0[co] = fmaf(acc, dY1v, m0[co]);
    }
    float4* mp = (float4*)(ws + OFF_MSGA0) + t * 4;
    mp[0] = make_float4(m0[0], m0[1], m0[2], m0[3]);
    mp[1] = make_float4(m0[4], m0[5], m0[6], m0[7]);
    mp[2] = make_float4(m0[8], m0[9], m0[10], m0[11]);
    mp[3] = make_float4(m0[12], m0[13], m0[14], m0[15]);
  }
}

// ---- stage A1: nets 1,3 -> m1[48] -> msgA1 (sorted, coalesced) ----
__global__ __launch_bounds__(256) void k_passA1(
    const int* __restrict__ src,
    const float* __restrict__ cI, const float* __restrict__ vI,
    const float* __restrict__ w,
    const float* __restrict__ w01, const float* __restrict__ b01,
    const float* __restrict__ w11, const float* __restrict__ b11,
    float* __restrict__ ws) {
  __shared__ __align__(16) float sW1a[64], sW1b[64], sc1[64], sc2[64];
  __shared__ __align__(16) float sW2T[2048];
  __shared__ __align__(16) float sP01[512], sP11[1536];
  __shared__ float sB01[16], sB11[48];
  int tid = threadIdx.x;
  if (tid < 32) {
    sW1a[tid] = ws[OFF_FW1A + 32 + tid];  sW1a[32 + tid] = ws[OFF_FW1A + 96 + tid];
    sW1b[tid] = ws[OFF_FW1B + 32 + tid];  sW1b[32 + tid] = ws[OFF_FW1B + 96 + tid];
    sc1[tid]  = ws[OFF_FC1 + 32 + tid];   sc1[32 + tid]  = ws[OFF_FC1 + 96 + tid];
    sc2[tid]  = ws[OFF_FC2 + 32 + tid];   sc2[32 + tid]  = ws[OFF_FC2 + 96 + tid];
  }
  for (int t = tid; t < 1024; t += 256) {
    sW2T[t] = ws[OFF_FW2T + 1024 + t];
    sW2T[1024 + t] = ws[OFF_FW2T + 3072 + t];
  }
  for (int t = tid; t < 512; t += 256) {
    int i = t >> 4, co = t & 15;
    sP01[co * 32 + i] = w01[t];
  }
  for (int t = tid; t < 1536; t += 256) {
    int i = t / 48, c = t - i * 48;
    sP11[c * 32 + i] = w11[t];
  }
  if (tid < 16) sB01[tid] = b01[tid];
  if (tid < 48) sB11[tid] = b11[tid];
  __syncthreads();

  const int* eorder = (const int*)ws + OFF_EORDER;
  const float4* ec = (const float4*)(ws + OFF_ECACHE);
  for (int t = blockIdx.x * blockDim.x + tid; t < NE;
       t += gridDim.x * blockDim.x) {
    int e = eorder[t];
    int s = src[e];
    float4 E4 = ec[e];
    float r = E4.x, ux = E4.y, uy = E4.z, uz = E4.w;
    float we = w[e];
    float cs = cI[s];
    float v0 = vI[3 * s + 0], v1 = vI[3 * s + 1], v2 = vI[3 * s + 2];
    float y10 = Y1C * uy, y11 = Y1C * uz, y12 = Y1C * ux;
    float y20 = Y2C1 * ux * uy, y21 = Y2C1 * uy * uz;
    float y22 = Y2C2 * (3.0f * uz * uz - 1.0f);
    float y23 = Y2C1 * ux * uz, y24 = Y2C3 * (ux * ux - uy * uy);
    float S00 = -S6C * y22 - S2C * y24;
    float S11 = 2.0f * S6C * y22;
    float S22 = -S6C * y22 + S2C * y24;
    float S01 = S2C * y21, S02 = S2C * y20, S12 = S2C * y23;
    float KV[3][3];
    KV[0][0] = K0C * v0; KV[0][1] = K0C * v1; KV[0][2] = K0C * v2;
    KV[1][0] = S2C * (y12 * v1 - y11 * v2);
    KV[1][1] = S2C * (y10 * v2 - y12 * v0);
    KV[1][2] = S2C * (y11 * v0 - y10 * v1);
    KV[2][0] = S00 * v0 + S01 * v1 + S02 * v2;
    KV[2][1] = S01 * v0 + S11 * v1 + S12 * v2;
    KV[2][2] = S02 * v0 + S12 * v1 + S22 * v2;

    float H[MID];
    float m1[CDIM * 3];
    mlpH_lds(sW1a, sW1b, sc1, sc2, sW2T, we, r, H);
    float cy0 = cs * y10, cy1 = cs * y11, cy2 = cs * y12;
#pragma unroll
    for (int co = 0; co < CDIM; ++co) {
      float acc = sB01[co];
#pragma unroll
      for (int i = 0; i < MID; ++i) acc = fmaf(H[i], sP01[co * 32 + i], acc);
      m1[co * 3 + 0] = acc * cy0;
      m1[co * 3 + 1] = acc * cy1;
      m1[co * 3 + 2] = acc * cy2;
    }
    mlpH_lds(sW1a + 32, sW1b + 32, sc1 + 32, sc2 + 32, sW2T + 1024, we, r, H);
#pragma unroll
    for (int co = 0; co < CDIM; ++co) {
#pragma unroll
      for (int f = 0; f < 3; ++f) {
        float acc = sB11[co * 3 + f];
#pragma unroll
        for (int i = 0; i < MID; ++i)
          acc = fmaf(H[i], sP11[(co * 3 + f) * 32 + i], acc);
        m1[co * 3 + 0] = fmaf(acc, KV[f][0], m1[co * 3 + 0]);
        m1[co * 3 + 1] = fmaf(acc, KV[f][1], m1[co * 3 + 1]);
        m1[co * 3 + 2] = fmaf(acc, KV[f][2], m1[co * 3 + 2]);
      }
    }
    float4* mp = (float4*)(ws + OFF_MSGA1) + t * 12;
#pragma unroll
    for (int q = 0; q < 12; ++q)
      mp[q] = make_float4(m1[4 * q], m1[4 * q + 1], m1[4 * q + 2], m1[4 * q + 3]);
  }
}

// ---- node update A: gather sorted messages + self + norm_bias ----
__global__ __launch_bounds__(256) void k_nodeA(
    const float* __restrict__ cI, const float* __restrict__ vI,
    const float* __restrict__ selfA0, const float* __restrict__ selfA1,
    const float* __restrict__ nbias0, const float* __restrict__ nbias1,
    float* __restrict__ ws) {
  int idx = blockIdx.x * blockDim.x + threadIdx.x;
  if (idx >= NN * CDIM) return;
  int n = idx >> 4, co = idx & 15;
  const int* rowptr = (const int*)ws + OFF_ROWPTR;
  int r0 = rowptr[n], r1 = rowptr[n + 1];
  const float* mA0 = ws + OFF_MSGA0;
  const float* mA1 = ws + OFF_MSGA1;
  float x0 = 0.0f, xa = 0.0f, xb = 0.0f, xc = 0.0f;
  for (int row = r0; row < r1; ++row) {
    x0 += mA0[row * 16 + co];
    xa += mA1[row * 48 + co * 3 + 0];
    xb += mA1[row * 48 + co * 3 + 1];
    xc += mA1[row * 48 + co * 3 + 2];
  }
  float dg = (float)(r1 - r0);
  float iv = 1.0f / fmaxf(dg, 1.0f);
  float mk = dg > 0.0f ? 1.0f : 0.0f;
  x0 = x0 * iv + selfA0[co] * cI[n] * mk;
  float n0 = sqrtf(x0 * x0 + 1e-12f);
  ws[OFF_H0N + idx] = fmaxf(n0 + nbias0[co], 0.0f) * (x0 / fmaxf(n0, EPSF));
  xa = xa * iv + selfA1[co] * vI[3 * n + 0] * mk;
  xb = xb * iv + selfA1[co] * vI[3 * n + 1] * mk;
  xc = xc * iv + selfA1[co] * vI[3 * n + 2] * mk;
  float nv = sqrtf(xa * xa + xb * xb + xc * xc + 1e-12f);
  float sc = fmaxf(nv + nbias1[co], 0.0f) / fmaxf(nv, EPSF);
  ws[OFF_H1N + idx * 3 + 0] = xa * sc;
  ws[OFF_H1N + idx * 3 + 1] = xb * sc;
  ws[OFF_H1N + idx * 3 + 2] = xc * sc;
}

// ---- stage B: nets 4,5 -> mB[6] -> msgB (sorted, coalesced) ----
__global__ __launch_bounds__(256) void k_passB(
    const int* __restrict__ src,
    const float* __restrict__ w,
    const float* __restrict__ wb01, const float* __restrict__ bb01,
    const float* __restrict__ wb11, const float* __restrict__ bb11,
    float* __restrict__ ws) {
  __shared__ __align__(16) float sW1a[64], sW1b[64], sc1[64], sc2[64];
  __shared__ __align__(16) float sW2T[2048];
  __shared__ __align__(16) float sPB01[1024], sPB11[3072];
  __shared__ float sBB01[32], sBB11[96];
  int tid = threadIdx.x;
  if (tid < 64) {
    sW1a[tid] = ws[OFF_FW1A + 128 + tid];
    sW1b[tid] = ws[OFF_FW1B + 128 + tid];
    sc1[tid] = ws[OFF_FC1 + 128 + tid];
    sc2[tid] = ws[OFF_FC2 + 128 + tid];
  }
  for (int t = tid; t < 2048; t += 256) sW2T[t] = ws[OFF_FW2T + 4096 + t];
  for (int t = tid; t < 1024; t += 256) {
    int i = t >> 5, c = t & 31;
    sPB01[c * 32 + i] = wb01[t];
  }
  for (int t = tid; t < 3072; t += 256) {
    int i = t / 96, c = t - i * 96;
    sPB11[c * 32 + i] = wb11[t];
  }
  if (tid < 32) sBB01[tid] = bb01[tid];
  if (tid < 96) sBB11[tid] = bb11[tid];
  __syncthreads();

  const int* eorder = (const int*)ws + OFF_EORDER;
  const float4* ec = (const float4*)(ws + OFF_ECACHE);
  float* msgB = ws + OFF_MSGB;
  for (int t = blockIdx.x * blockDim.x + tid; t < NE;
       t += gridDim.x * blockDim.x) {
    int e = eorder[t];
    int s = src[e];
    float4 E4 = ec[e];
    float r = E4.x, ux = E4.y, uy = E4.z, uz = E4.w;
    float we = w[e];
    float y10 = Y1C * uy, y11 = Y1C * uz, y12 = Y1C * ux;
    float y20 = Y2C1 * ux * uy, y21 = Y2C1 * uy * uz;
    float y22 = Y2C2 * (3.0f * uz * uz - 1.0f);
    float y23 = Y2C1 * ux * uz, y24 = Y2C3 * (ux * ux - uy * uy);
    float S00 = -S6C * y22 - S2C * y24;
    float S11 = 2.0f * S6C * y22;
    float S22 = -S6C * y22 + S2C * y24;
    float S01 = S2C * y21, S02 = S2C * y20, S12 = S2C * y23;

    float H[MID];
    mlpH_lds(sW1a, sW1b, sc1, sc2, sW2T, we, r, H);
    const float* h0p = ws + OFF_H0N + s * CDIM;
    float A0 = 0.0f, A1 = 0.0f;
#pragma unroll
    for (int ci = 0; ci < CDIM; ++ci) {
      float t0 = h0p[ci];
      float R0 = sBB01[ci];
      float R1 = sBB01[CDIM + ci];
#pragma unroll
      for (int i = 0; i < MID; ++i) {
        float hi = H[i];
        R0 = fmaf(hi, sPB01[ci * 32 + i], R0);
        R1 = fmaf(hi, sPB01[(CDIM + ci) * 32 + i], R1);
      }
      A0 = fmaf(R0, t0, A0);
      A1 = fmaf(R1, t0, A1);
    }
    mlpH_lds(sW1a + 32, sW1b + 32, sc1 + 32, sc2 + 32, sW2T + 1024, we, r, H);
    const float* h1p = ws + OFF_H1N + s * CDIM * 3;
    float G[2][3][3];
#pragma unroll
    for (int o = 0; o < 2; ++o)
#pragma unroll
      for (int f = 0; f < 3; ++f) {
        G[o][f][0] = 0.0f; G[o][f][1] = 0.0f; G[o][f][2] = 0.0f;
      }
#pragma unroll
    for (int ci = 0; ci < CDIM; ++ci) {
      float t1b0 = h1p[ci * 3 + 0], t1b1 = h1p[ci * 3 + 1], t1b2 = h1p[ci * 3 + 2];
#pragma unroll
      for (int o = 0; o < 2; ++o) {
#pragma unroll
        for (int f = 0; f < 3; ++f) {
          float R = sBB11[o * 48 + ci * 3 + f];
#pragma unroll
          for (int i = 0; i < MID; ++i)
            R = fmaf(H[i], sPB11[(o * 48 + ci * 3 + f) * 32 + i], R);
          G[o][f][0] = fmaf(R, t1b0, G[o][f][0]);
          G[o][f][1] = fmaf(R, t1b1, G[o][f][1]);
          G[o][f][2] = fmaf(R, t1b2, G[o][f][2]);
        }
      }
    }
#pragma unroll
    for (int o = 0; o < 2; ++o) {
      float Ao = (o == 0) ? A0 : A1;
      float mB0 = Ao * y10 + K0C * G[o][0][0]
                + S2C * (y12 * G[o][1][1] - y11 * G[o][1][2])
                + S00 * G[o][2][0] + S01 * G[o][2][1] + S02 * G[o][2][2];
      float mB1 = Ao * y11 + K0C * G[o][0][1]
                + S2C * (y10 * G[o][1][2] - y12 * G[o][1][0])
                + S01 * G[o][2][0] + S11 * G[o][2][1] + S12 * G[o][2][2];
      float mB2 = Ao * y12 + K0C * G[o][0][2]
                + S2C * (y11 * G[o][1][0] - y10 * G[o][1][1])
                + S02 * G[o][2][0] + S12 * G[o][2][1] + S22 * G[o][2][2];
      msgB[t * 6 + o * 3 + 0] = mB0;
      msgB[t * 6 + o * 3 + 1] = mB1;
      msgB[t * 6 + o * 3 + 2] = mB2;
    }
  }
}

// ---- node update B: gather + self -> out ----
__global__ __launch_bounds__(256) void k_nodeB(
    const float* __restrict__ selfB1, float* __restrict__ out,
    const float* __restrict__ ws) {
  int idx = blockIdx.x * blockDim.x + threadIdx.x;
  if (idx >= NN * 6) return;
  int n = idx / 6;
  int q = idx - n * 6;
  int o = q / 3, a = q - o * 3;
  const int* rowptr = (const int*)ws + OFF_ROWPTR;
  int r0 = rowptr[n], r1 = rowptr[n + 1];
  const float* msgB = ws + OFF_MSGB;
  float sum = 0.0f;
  for (int row = r0; row < r1; ++row) sum += msgB[row * 6 + q];
  float dg = (float)(r1 - r0);
  float iv = 1.0f / fmaxf(dg, 1.0f);
  float mk = dg > 0.0f ? 1.0f : 0.0f;
  const float* h1p = ws + OFF_H1N + n * CDIM * 3;
  float self = 0.0f;
#pragma unroll
  for (int ci = 0; ci < CDIM; ++ci)
    self = fmaf(selfB1[o * CDIM + ci], h1p[ci * 3 + a], self);
  out[idx] = sum * iv + self * mk;
}

extern "C" void kernel_launch(void* const* d_in, const int* in_sizes, int n_in,
                              void* d_out, int out_size, void* d_ws, size_t ws_size,
                              hipStream_t stream) {
  (void)in_sizes; (void)n_in; (void)out_size; (void)ws_size;
  const int* src = (const int*)d_in[0];
  const int* dst = (const int*)d_in[1];
  const float* pos = (const float*)d_in[2];
  const float* cI = (const float*)d_in[3];
  const float* vI = (const float*)d_in[4];
  const float* w = (const float*)d_in[5];
  const float* rW1 = (const float*)d_in[6];
  const float* rb1 = (const float*)d_in[7];
  const float* rg1 = (const float*)d_in[8];
  const float* rbe1 = (const float*)d_in[9];
  const float* rW2 = (const float*)d_in[10];
  const float* rb2 = (const float*)d_in[11];
  const float* rg2 = (const float*)d_in[12];
  const float* rbe2 = (const float*)d_in[13];
  const float* w3_a00 = (const float*)d_in[14];
  const float* b3_a00 = (const float*)d_in[15];
  const float* w3_a01 = (const float*)d_in[16];
  const float* b3_a01 = (const float*)d_in[17];
  const float* w3_a10 = (const float*)d_in[18];
  const float* b3_a10 = (const float*)d_in[19];
  const float* w3_a11 = (const float*)d_in[20];
  const float* b3_a11 = (const float*)d_in[21];
  const float* w3_b01 = (const float*)d_in[22];
  const float* b3_b01 = (const float*)d_in[23];
  const float* w3_b11 = (const float*)d_in[24];
  const float* b3_b11 = (const float*)d_in[25];
  const float* selfA0 = (const float*)d_in[26];
  const float* selfA1 = (const float*)d_in[27];
  const float* selfB1 = (const float*)d_in[28];
  const float* nbias0 = (const float*)d_in[29];
  const float* nbias1 = (const float*)d_in[30];
  float* ws = (float*)d_ws;
  float* out = (float*)d_out;

  hipMemsetAsync(d_ws, 0, (size_t)ZERO_WORDS * 4, stream);

  k_pass1<<<1250, 256, 0, stream>>>(src, dst, pos, w, ws);
  k_fin1<<<1, 192, 0, stream>>>(rW1, rb1, rg1, rbe1, ws);
  k_scan<<<1, 256, 0, stream>>>(ws);
  k_scatter<<<1250, 256, 0, stream>>>(dst, ws);
  k_stats2<<<dim3(64, 6, 4), 256, 0, stream>>>(w, rW2, rb2, ws);
  k_fin2<<<1, 192, 0, stream>>>(rb2, rg2, rbe2, ws);
  k_fold2<<<24, 256, 0, stream>>>(rW2, ws);
  k_passA0<<<625, 256, 0, stream>>>(src, cI, vI, w, w3_a00, b3_a00,
                                    w3_a10, b3_a10, ws);
  k_passA1<<<625, 256, 0, stream>>>(src, cI, vI, w, w3_a01, b3_a01,
                                    w3_a11, b3_a11, ws);
  k_nodeA<<<1250, 256, 0, stream>>>(cI, vI, selfA0, selfA1, nbias0, nbias1, ws);
  k_passB<<<625, 256, 0, stream>>>(src, w, w3_b01, b3_b01, w3_b11, b3_b11, ws);
  k_nodeB<<<469, 256, 0, stream>>>(selfB1, out, ws);
}